// Round 6
// baseline (411.489 us; speedup 1.0000x reference)
//
#include <hip/hip_runtime.h>
#include <hip/hip_bf16.h>

#define B_ 16
#define C_ 512
#define N_ 4096
#define EPSV 1e-6f

typedef __attribute__((ext_vector_type(8))) short bffrag;     // 8 bf16 (4 VGPR) MFMA A/B frag
typedef __attribute__((ext_vector_type(4))) float f32x4;      // MFMA C/D frag
typedef __attribute__((ext_vector_type(2))) unsigned short us2;
typedef __attribute__((ext_vector_type(4))) unsigned short us4;
typedef __attribute__((ext_vector_type(8))) unsigned short us8;

__device__ __forceinline__ unsigned short f2bf(float f){
  unsigned u = __float_as_uint(f);
  u += 0x7fffu + ((u >> 16) & 1u);   // RNE; inputs are finite gaussians
  return (unsigned short)(u >> 16);
}

// async global->LDS, 16B/lane; LDS base must be wave-uniform, HW scatters
// lane i to base + i*16. Global source IS per-lane -> swizzled LDS layouts
// are done by pre-swizzling the global source address (m173 pattern).
__device__ __forceinline__ void gload_lds16(const void* g, void* l){
  __builtin_amdgcn_global_load_lds(
      (__attribute__((address_space(1))) void*)g,
      (__attribute__((address_space(3))) void*)l, 16, 0, 0);
}

#define SBAR()  __builtin_amdgcn_s_barrier()
#define SCHED0() __builtin_amdgcn_sched_barrier(0)
#define WAITV(N) asm volatile("s_waitcnt vmcnt(" #N ")" ::: "memory")
#define WAITL0() asm volatile("s_waitcnt lgkmcnt(0)" ::: "memory")
#define PRIO(N) __builtin_amdgcn_s_setprio(N)

// ---------------------------------------------------------------------------
// K1: fused reduce+prep. Block = (b, 64-n strip).
// R6: 512 threads/block (8 waves). Grid is fixed at 1024 blocks = 4/CU, so
// 256 threads capped occupancy at 50% theoretical (34% measured, R5). At
// 512 threads: 4 blocks x 8 waves = 32 waves/CU = 100% theoretical ->
// doubles outstanding loads. LDS unchanged at 16896 B (sdA/sdB now [32][64];
// qtl [128][66] alias). Transpose: rp=t>>4 row-pair, o=t&15 chunk; one shot
// covers the 128-c chunk; per wave-inst 4 rows x 256B contiguous segments
// (full lines inside one inst). LDS read bank = (8o+e+rp)%32 -> 4 lanes/bank
// (1.58x) on 16 us2 reads -- accepted for the 2x occupancy.
// ---------------------------------------------------------------------------
__global__ __launch_bounds__(512) void k_prep(const float* __restrict__ x,
    unsigned short* __restrict__ Ph, unsigned short* __restrict__ Pt,
    float* __restrict__ vsum, float* __restrict__ sqg,
    float* __restrict__ tpart){
  __shared__ __align__(16) char smem[16896];
  float (*sdA)[64] = (float(*)[64])smem;                // 8KB   (pass A)
  float (*sdB)[64] = (float(*)[64])(smem + 8192);       // 8KB   (pass A)
  float* sql = (float*)(smem + 16384);                  // 256B  (pass A out)
  float* rql = (float*)(smem + 16640);                  // 256B  (pass A out)
  unsigned short* qtl = (unsigned short*)smem;          // pass-B alias [128][66]

  const int t = threadIdx.x;
  const int b = blockIdx.x >> 6, strip = blockIdx.x & 63, n0 = strip * 64;
  const int rg = t >> 4, n4 = t & 15;                   // rg 0..31
  const float* xs = x + (size_t)b * C_ * N_ + n0;

  // pass A: column sums over all 512 c (16 rows/thread)
  float4 s4 = {0,0,0,0}, s24 = {0,0,0,0};
  #pragma unroll 8
  for (int k = 0; k < 16; ++k){
    float4 v = *(const float4*)&xs[(size_t)(k * 32 + rg) * N_ + n4 * 4];
    s4.x += v.x; s4.y += v.y; s4.z += v.z; s4.w += v.w;
    s24.x += v.x * v.x; s24.y += v.y * v.y;
    s24.z += v.z * v.z; s24.w += v.w * v.w;
  }
  *(float4*)&sdA[rg][n4 * 4] = s4;
  *(float4*)&sdB[rg][n4 * 4] = s24;
  __syncthreads();
  if (t < 64){
    float s = 0.f, s2 = 0.f;
    #pragma unroll
    for (int g2 = 0; g2 < 32; ++g2){ s += sdA[g2][t]; s2 += sdB[g2][t]; }
    float rn = 1.0f / sqrtf(s2);
    float sq = sqrtf(rn);
    vsum[b * N_ + n0 + t] = s;
    sqg [b * N_ + n0 + t] = sq;
    sql[t] = sq;
    rql[t] = rn * (s * rn + EPSV);
  }
  __syncthreads();
  float4 sq4 = *(float4*)&sql[n4 * 4];
  float4 rq4 = *(float4*)&rql[n4 * 4];
  __syncthreads();                       // scales in regs; smem now free for qtl

  unsigned short* Php = Ph + (size_t)b * C_ * N_ + n0;
  float* tpp = tpart + ((size_t)b * 64 + strip) * C_;
  const int rp = t >> 4, o = t & 15;     // transpose roles: row-pair, chunk
  unsigned short* P0 = Pt + ((size_t)b * N_ + n0 + rp * 2) * C_;
  unsigned short* P1 = P0 + C_;
  const int clb = o * 8;

  for (int h = 0; h < 4; ++h){
    // pass B over c-local 0..127 (c = h*128 + cl); x re-read is L2-hot
    #pragma unroll 4
    for (int k = 0; k < 4; ++k){
      int cl = k * 32 + rg, c = h * 128 + cl;
      float4 v = *(const float4*)&xs[(size_t)c * N_ + n4 * 4];
      us2 p0, p1;
      p0.x = f2bf(v.x * sq4.x); p0.y = f2bf(v.y * sq4.y);
      p1.x = f2bf(v.z * sq4.z); p1.y = f2bf(v.w * sq4.w);
      us4 ph; ph.x = p0.x; ph.y = p0.y; ph.z = p1.x; ph.w = p1.y;
      *(us4*)&Php[(size_t)c * N_ + n4 * 4] = ph;
      *(us2*)&qtl[cl * 66 + n4 * 4]     = p0;   // 4B-aligned; 2 lanes/bank
      *(us2*)&qtl[cl * 66 + n4 * 4 + 2] = p1;
      float tp = v.x * rq4.x + v.y * rq4.y + v.z * rq4.z + v.w * rq4.w;
      tp += __shfl_down(tp, 8, 16);
      tp += __shfl_down(tp, 4, 16);
      tp += __shfl_down(tp, 2, 16);
      tp += __shfl_down(tp, 1, 16);
      if (n4 == 0) tpp[c] = tp;
    }
    __syncthreads();
    // transpose store: rows 2rp, 2rp+1; chunk clb = o*8 (covers all 128 c).
    // Per wave-inst: 4 rows x 256B contiguous global segments.
    {
      us8 w0, w1;
      #pragma unroll
      for (int e = 0; e < 8; ++e){
        us2 v = *(const us2*)&qtl[(clb + e) * 66 + rp * 2];
        w0[e] = v.x; w1[e] = v.y;
      }
      *(us8*)&P0[h * 128 + clb] = w0;
      *(us8*)&P1[h * 128 + clb] = w1;
    }
    __syncthreads();                     // qtl reads done before next chunk
  }
}

// ---------------------------------------------------------------------------
// K2: GEMM1  matrix = Ph @ Ph^T per batch, K=4096, bf16 out.
// 4 waves x 64x64 acc, BK=64. 3-buffer LDS (96KB, CU has it idle at
// 1 block/CU) + 2-DEEP prefetch: WAITV(16) keeps two 8-load stages in
// flight across barriers -> covers ~2x tile latency. setprio around MFMA.
// ---------------------------------------------------------------------------
__global__ __launch_bounds__(256) void k_gemm1(const unsigned short* __restrict__ Ph,
    unsigned short* __restrict__ Ab, const float* __restrict__ tpart,
    float* __restrict__ tvec){
  const int bid = blockIdx.x;
  if (bid >= 256){                       // tail: tvec[b*C+c] = sum_strips tpart
    const int base = (bid - 256) * 512;
    for (int u = threadIdx.x; u < 512; u += 256){
      int i = base + u;
      const float* tp = tpart + (size_t)(i >> 9) * 64 * C_ + (i & 511);
      float s = 0.f;
      #pragma unroll 8
      for (int k = 0; k < 64; ++k) s += tp[(size_t)k * C_];
      tvec[i] = s;
    }
    return;
  }
  // bijective bid -> (b, c0, m0): XCD xcd = bid&7 owns 2x2 tile quads
  const int xcd = bid & 7, sq_ = bid >> 3;
  const int qg = xcd * 8 + (sq_ >> 2), sub = sq_ & 3;
  const int b = qg >> 2, qd = qg & 3;
  const int c0 = ((qd >> 1) * 2 + (sub >> 1)) * 128;
  const int m0 = ((qd & 1) * 2 + (sub & 1)) * 128;

  __shared__ unsigned short As[3][8192], Bs[3][8192];   // [buf][128 rows][64 k]

  const int t = threadIdx.x, lane = t & 63, wave = t >> 6;
  const int wr = (wave & 1) * 64, wc = (wave >> 1) * 64;
  const int fr = lane & 15, quad = lane >> 4;
  const int rxor = (fr & 7) << 4;        // read-side swizzle (row&7 == fr&7)

  // staging: call q covers rows q*32 + (t>>3); source chunk = (t&7) ^ (row&7)
  const int rq = t >> 3;
  const int csel = ((t & 7) ^ (rq & 7)) * 8;
  const unsigned short* Aga = Ph + (size_t)(b * C_ + c0 + rq) * N_ + csel;
  const unsigned short* Bga = Ph + (size_t)(b * C_ + m0 + rq) * N_ + csel;
  const int lo = wave * 512;             // elements; HW adds lane*8

  f32x4 acc[4][4];
  #pragma unroll
  for (int i = 0; i < 4; ++i)
    #pragma unroll
    for (int j = 0; j < 4; ++j) acc[i][j] = (f32x4){0.f, 0.f, 0.f, 0.f};

  auto stage = [&](int bufi, int k0){
    gload_lds16(Aga + k0,           &As[bufi][lo]);
    gload_lds16(Aga + 32 * N_ + k0, &As[bufi][2048 + lo]);
    gload_lds16(Aga + 64 * N_ + k0, &As[bufi][4096 + lo]);
    gload_lds16(Aga + 96 * N_ + k0, &As[bufi][6144 + lo]);
    gload_lds16(Bga + k0,           &Bs[bufi][lo]);
    gload_lds16(Bga + 32 * N_ + k0, &Bs[bufi][2048 + lo]);
    gload_lds16(Bga + 64 * N_ + k0, &Bs[bufi][4096 + lo]);
    gload_lds16(Bga + 96 * N_ + k0, &Bs[bufi][6144 + lo]);
  };

  stage(0, 0);
  stage(1, 64);
  int cur = 0, nxt = 2;
  for (int kc = 0; kc < 64; ++kc){
    if (kc < 62){
      stage(nxt, (kc + 2) * 64);         // 8 loads; 2 stages stay in flight
      nxt = (nxt == 2) ? 0 : nxt + 1;
      SCHED0();
      WAITV(16);                         // oldest 8 (tile kc) landed
    } else if (kc == 62){
      WAITV(8);
    } else {
      WAITV(0);
    }
    SBAR();                              // all waves have buf[cur] landed
    SCHED0();
    const char* Ac = (const char*)&As[cur][0];
    const char* Bc = (const char*)&Bs[cur][0];
    PRIO(1);
    #pragma unroll
    for (int kk = 0; kk < 2; ++kk){
      bffrag af[4], bfr[4];
      #pragma unroll
      for (int i = 0; i < 4; ++i)
        af[i] = *(const bffrag*)(Ac +
            (((wr + i * 16 + fr) * 128 + kk * 64 + quad * 16) ^ rxor));
      #pragma unroll
      for (int j = 0; j < 4; ++j)
        bfr[j] = *(const bffrag*)(Bc +
            (((wc + j * 16 + fr) * 128 + kk * 64 + quad * 16) ^ rxor));
      #pragma unroll
      for (int i = 0; i < 4; ++i)
        #pragma unroll
        for (int j = 0; j < 4; ++j)
          acc[i][j] = __builtin_amdgcn_mfma_f32_16x16x32_bf16(af[i], bfr[j], acc[i][j], 0, 0, 0);
    }
    PRIO(0);
    SCHED0();
    SBAR();                              // all waves done reading buf[cur]
    cur = (cur == 2) ? 0 : cur + 1;
  }

  unsigned short* op = Ab + (size_t)b * C_ * C_;
  #pragma unroll
  for (int i = 0; i < 4; ++i)
    #pragma unroll
    for (int r = 0; r < 4; ++r){
      int c = c0 + wr + i * 16 + quad * 4 + r;
      #pragma unroll
      for (int j = 0; j < 4; ++j)
        op[(size_t)c * C_ + m0 + wc + j * 16 + fr] = f2bf(acc[i][j][r]);
    }
}

// ---------------------------------------------------------------------------
// K3: GEMM2 + epilogue. A = Ab[c][m], B = Pt[n][m], K=512, BK=32.
// 3-buffer LDS (48KB, 3 blocks/CU) + 2-DEEP prefetch WAITV(8); the
// epilogue vsum/sqg loads are hoisted BEFORE the prologue stages so they
// retire under the first WAITV (vmcnt accounting stays exact). setprio
// around MFMA. Epilogue: 4-pass LDS bounce -> float4 coalesced RMW.
// ---------------------------------------------------------------------------
__global__ __launch_bounds__(256) void k_gemm2(const float* __restrict__ x,
    const unsigned short* __restrict__ Ab, const unsigned short* __restrict__ Pt,
    const float* __restrict__ vsum, const float* __restrict__ sqg,
    const float* __restrict__ tvec, const float* __restrict__ gamma,
    float* __restrict__ out){
  const int b  = blockIdx.y;
  const int c0 = (blockIdx.x >> 5) * 128, n0 = (blockIdx.x & 31) * 128;

  __shared__ __align__(16) char smem[49152];
  unsigned short* As0 = (unsigned short*)smem;   // [3][4096] us = 24KB
  unsigned short* Bs0 = As0 + 12288;             // [3][4096] us = 24KB
  float (*eps)[132]   = (float(*)[132])smem;     // epilogue 32x132 fp32 = 16.9KB
  __shared__ float tl[128];

  const int t = threadIdx.x, lane = t & 63, wave = t >> 6;
  // tvec load + tl write FIRST: compiler's vmcnt wait for the ds_write
  // lands before any stage loads are issued.
  if (t < 128) tl[t] = 1.0f / ((float)N_ + tvec[b * C_ + c0 + t]);
  const int wr = (wave & 1) * 64, wc = (wave >> 1) * 64;
  const int fr = lane & 15, quad = lane >> 4;
  const int rxor = ((fr >> 1) & 3) << 4;  // read swizzle ((row>>1)&3 == (fr>>1)&3)

  // epilogue scale vectors, hoisted ahead of the prologue stages: they are
  // the OLDEST vmem ops, so the first WAITV(8) retires them with tile 0.
  const int col4 = (t & 31) * 4;
  float4 v4 = *(const float4*)&vsum[(size_t)b * N_ + n0 + col4];
  float4 s4 = *(const float4*)&sqg [(size_t)b * N_ + n0 + col4];

  // staging: call q covers rows q*64 + (t>>2); chunk = (t&3) ^ ((row>>1)&3)
  const int r2 = t >> 2;
  const int cse = ((t & 3) ^ ((t >> 3) & 3)) * 8;
  const unsigned short* Ag = Ab + (size_t)b * C_ * C_ + (size_t)(c0 + r2) * C_ + cse;
  const unsigned short* Bg = Pt + ((size_t)b * N_ + n0 + r2) * C_ + cse;
  const int lo = wave * 512;             // elements; HW adds lane*8

  f32x4 acc[4][4];
  #pragma unroll
  for (int i = 0; i < 4; ++i)
    #pragma unroll
    for (int j = 0; j < 4; ++j) acc[i][j] = (f32x4){0.f, 0.f, 0.f, 0.f};

  auto stage = [&](int bufi, int k0){
    gload_lds16(Ag + k0,           As0 + bufi * 4096 + lo);
    gload_lds16(Ag + 64 * C_ + k0, As0 + bufi * 4096 + 2048 + lo);
    gload_lds16(Bg + k0,           Bs0 + bufi * 4096 + lo);
    gload_lds16(Bg + 64 * C_ + k0, Bs0 + bufi * 4096 + 2048 + lo);
  };

  stage(0, 0);
  stage(1, 32);
  int cur = 0, nxt = 2;
  for (int kc = 0; kc < 16; ++kc){
    if (kc < 14){
      stage(nxt, (kc + 2) * 32);         // 4 loads; 2 stages stay in flight
      nxt = (nxt == 2) ? 0 : nxt + 1;
      SCHED0();
      WAITV(8);                          // oldest 4 (tile kc) landed
    } else if (kc == 14){
      WAITV(4);
    } else {
      WAITV(0);
    }
    SBAR();
    SCHED0();
    const char* Ac = (const char*)(As0 + cur * 4096);
    const char* Bc = (const char*)(Bs0 + cur * 4096);
    bffrag af[4], bfr[4];
    #pragma unroll
    for (int i = 0; i < 4; ++i)
      af[i] = *(const bffrag*)(Ac + (((wr + i * 16 + fr) * 64 + quad * 16) ^ rxor));
    #pragma unroll
    for (int j = 0; j < 4; ++j)
      bfr[j] = *(const bffrag*)(Bc + (((wc + j * 16 + fr) * 64 + quad * 16) ^ rxor));
    PRIO(1);
    #pragma unroll
    for (int i = 0; i < 4; ++i)
      #pragma unroll
      for (int j = 0; j < 4; ++j)
        acc[i][j] = __builtin_amdgcn_mfma_f32_16x16x32_bf16(af[i], bfr[j], acc[i][j], 0, 0, 0);
    PRIO(0);
    SCHED0();
    SBAR();                              // all waves done reading buf[cur]
    cur = (cur == 2) ? 0 : cur + 1;
  }

  // ---- epilogue: 4 passes, each bounces 32 c-rows x 128 n-cols via LDS ----
  const float g = gamma[0];
  const size_t bofs = (size_t)b * C_ * N_;
  const int rbase = (wave & 1) * 16 + quad * 4;        // LDS row for writes

  #pragma unroll
  for (int i = 0; i < 4; ++i){
    // write acc[i][*][*] -> eps[32][132]  (2-way banks = free)
    #pragma unroll
    for (int r = 0; r < 4; ++r)
      #pragma unroll
      for (int j = 0; j < 4; ++j)
        eps[rbase + r][wc + j * 16 + fr] = acc[i][j][r];
    WAITL0();
    SCHED0();
    SBAR();
    SCHED0();
    // read back as float4 rows, fused RMW (512B contiguous per wave-inst)
    #pragma unroll
    for (int p = 0; p < 4; ++p){
      int row = p * 8 + (t >> 5);                      // 0..31
      int cg  = ((row >> 4) << 6) + i * 16 + (row & 15);   // c offset in tile
      float4 a  = *(const float4*)&eps[row][col4];
      const float* xr = x   + bofs + (size_t)(c0 + cg) * N_ + n0;
      float* orow     = out + bofs + (size_t)(c0 + cg) * N_ + n0;
      float4 xv = *(const float4*)&xr[col4];
      float tlc = tl[cg];
      float4 o;
      o.x = xv.x + g * ((v4.x + s4.x * a.x) * tlc);
      o.y = xv.y + g * ((v4.y + s4.y * a.y) * tlc);
      o.z = xv.z + g * ((v4.z + s4.z * a.z) * tlc);
      o.w = xv.w + g * ((v4.w + s4.w * a.w) * tlc);
      *(float4*)&orow[col4] = o;
    }
    SCHED0();
    SBAR();                              // reads done before next pass writes
    SCHED0();
  }
}

// ---------------------------------------------------------------------------
extern "C" void kernel_launch(void* const* d_in, const int* in_sizes, int n_in,
                              void* d_out, int out_size, void* d_ws, size_t ws_size,
                              hipStream_t stream){
  const float* x     = (const float*)d_in[0];
  const float* gamma = (const float*)d_in[1];
  float* out = (float*)d_out;
  char* ws = (char*)d_ws;

  // ws layout (bytes):
  unsigned short* Ph = (unsigned short*)(ws);              //  67,108,864
  unsigned short* Pt = (unsigned short*)(ws + 67108864);   //  67,108,864
  unsigned short* Ab = (unsigned short*)(ws + 134217728);  //   8,388,608
  float* tpart = (float*)(ws + 142606336);                 //   2,097,152
  float* vsum  = (float*)(ws + 144703488);                 //     262,144
  float* sqg   = (float*)(ws + 144965632);                 //     262,144
  float* tvec  = (float*)(ws + 145227776);                 //      32,768
  // total 145,260,544 bytes

  k_prep<<<dim3(B_ * 64), 512, 0, stream>>>(x, Ph, Pt, vsum, sqg, tpart);
  k_gemm1<<<dim3(272), 256, 0, stream>>>(Ph, Ab, tpart, tvec);
  k_gemm2<<<dim3(128, B_), 256, 0, stream>>>(x, Ab, Pt, vsum, sqg, tvec, gamma, out);
}